// Round 3
// baseline (655.156 us; speedup 1.0000x reference)
//
#include <hip/hip_runtime.h>
#include <hip/hip_bf16.h>
#include <stdint.h>

#define NF 64
#define NC 40
#define SCAN_BLK 1024  // elements scanned per block (256 threads x 4)

// ---------------------------------------------------------------------------
// Detect whether edge_index was uploaded as int32 or int64.
// For int64 (values < 2^31), every odd 32-bit word is 0.
// flag = 1 -> int32, flag = 0 -> int64.
// ---------------------------------------------------------------------------
__global__ void detect_dtype_kernel(const unsigned int* __restrict__ p, int* __restrict__ flag,
                                    int n_check) {
    __shared__ int s_any;
    if (threadIdx.x == 0) s_any = 0;
    __syncthreads();
    int any = 0;
    for (int i = threadIdx.x; i < n_check; i += blockDim.x) {
        if (p[2 * i + 1] != 0u) any = 1;
    }
    if (any) atomicOr(&s_any, 1);
    __syncthreads();
    if (threadIdx.x == 0) *flag = s_any;
}

__device__ __forceinline__ long long load_idx(const void* p, long long i, int is32) {
    if (is32) return (long long)((const int*)p)[i];
    return ((const long long*)p)[i];
}

__global__ void zero_cnt_kernel(int* __restrict__ cnt, int N) {
    int i = blockIdx.x * blockDim.x + threadIdx.x;
    if (i < N) cnt[i] = 0;
}

// cnt[col[e]] += 1  (in-degree, without self loop)
__global__ void count_kernel(const void* __restrict__ ei, int* __restrict__ cnt,
                             const int* __restrict__ flag, long long E) {
    long long e = (long long)blockIdx.x * blockDim.x + threadIdx.x;
    if (e >= E) return;
    int is32 = *flag;
    int c = (int)load_idx(ei, E + e, is32);
    atomicAdd(&cnt[c], 1);
}

// Per-block exclusive scan of cnt into row_ptr (block-local), block totals -> aux
__global__ void scanA_kernel(const int* __restrict__ cnt, int* __restrict__ row_ptr,
                             int* __restrict__ aux, int N) {
    __shared__ int sd[256];
    int t = threadIdx.x;
    int base = blockIdx.x * SCAN_BLK + t * 4;
    int v[4];
    int s = 0;
#pragma unroll
    for (int j = 0; j < 4; ++j) {
        v[j] = (base + j < N) ? cnt[base + j] : 0;
        s += v[j];
    }
    sd[t] = s;
    __syncthreads();
#pragma unroll
    for (int off = 1; off < 256; off <<= 1) {
        int a = (t >= off) ? sd[t - off] : 0;
        __syncthreads();
        sd[t] += a;
        __syncthreads();
    }
    int run = sd[t] - s;  // exclusive offset of this thread within block
#pragma unroll
    for (int j = 0; j < 4; ++j) {
        if (base + j < N) row_ptr[base + j] = run;
        run += v[j];
    }
    if (t == 255) aux[blockIdx.x] = sd[255];
}

// Exclusive scan of block totals (nb <= 128), single block of 128 threads
__global__ void scanB_kernel(int* __restrict__ aux, int nb) {
    __shared__ int sd[128];
    int t = threadIdx.x;
    int v = (t < nb) ? aux[t] : 0;
    sd[t] = v;
    __syncthreads();
#pragma unroll
    for (int off = 1; off < 128; off <<= 1) {
        int a = (t >= off) ? sd[t - off] : 0;
        __syncthreads();
        sd[t] += a;
        __syncthreads();
    }
    if (t < nb) aux[t] = sd[t] - v;
}

// row_ptr[i] += aux[block(i)]; dinv[i] = rsqrt(1+cnt[i]); cnt[i] = 0 (reused as fill ctr)
__global__ void scanC_kernel(int* __restrict__ row_ptr, const int* __restrict__ aux,
                             int* __restrict__ cnt, float* __restrict__ dinv, int N, int E) {
    int i = blockIdx.x * blockDim.x + threadIdx.x;
    if (i < N) {
        row_ptr[i] += aux[i >> 10];
        int c = cnt[i];
        dinv[i] = rsqrtf(1.0f + (float)c);
        cnt[i] = 0;  // becomes the fill counter
    }
    if (i == 0) row_ptr[N] = E;
}

// csr_src[row_ptr[col]++] = row
__global__ void fill_kernel(const void* __restrict__ ei, const int* __restrict__ row_ptr,
                            int* __restrict__ fill, int* __restrict__ csr_src,
                            const int* __restrict__ flag, long long E) {
    long long e = (long long)blockIdx.x * blockDim.x + threadIdx.x;
    if (e >= E) return;
    int is32 = *flag;
    int r = (int)load_idx(ei, e, is32);
    int c = (int)load_idx(ei, E + e, is32);
    int pos = row_ptr[c] + atomicAdd(&fill[c], 1);
    csr_src[pos] = r;
}

// z[i][c] = dinv[i] * sum_f x[i][f] * W[c][f]    (v0 = D^{-1/2} x W^T)
__global__ void zgemm_kernel(const float* __restrict__ x, const float* __restrict__ W,
                             const float* __restrict__ dinv, float* __restrict__ z, int N) {
    __shared__ float4 sW[NC * (NF / 4)];
    __shared__ float sZ[256 * (NC + 1)];
    for (int i = threadIdx.x; i < NC * (NF / 4); i += blockDim.x)
        sW[i] = ((const float4*)W)[i];
    __syncthreads();

    int base = blockIdx.x * 256;
    int node = base + threadIdx.x;
    if (node < N) {
        float4 hv[NF / 4];
        const float4* hp = (const float4*)(x + (long long)node * NF);
#pragma unroll
        for (int i = 0; i < NF / 4; ++i) hv[i] = hp[i];
        float di = dinv[node];
#pragma unroll
        for (int c = 0; c < NC; ++c) {
            float4 a = {0.f, 0.f, 0.f, 0.f};
#pragma unroll
            for (int i = 0; i < NF / 4; ++i) {
                float4 w = sW[c * (NF / 4) + i];
                a.x += w.x * hv[i].x;
                a.y += w.y * hv[i].y;
                a.z += w.z * hv[i].z;
                a.w += w.w * hv[i].w;
            }
            sZ[threadIdx.x * (NC + 1) + c] = di * ((a.x + a.y) + (a.z + a.w));
        }
    }
    __syncthreads();

    int nvalid = N - base;
    if (nvalid > 256) nvalid = 256;
    float* zp = z + (long long)base * NC;
    for (int idx = threadIdx.x; idx < nvalid * NC; idx += 256) {
        int n = idx / NC;
        int c = idx - n * NC;
        zp[idx] = sZ[n * (NC + 1) + c];
    }
}

// One wave per node, lanes 0..39 = class dims.
// vout[i] = dinv[i]^2 * (vin[i] + sum_{s in in(i)} vin[s])
// Neighbor indices prefetched lane-parallel (1 coalesced load), broadcast via shfl.
__global__ void hop_kernel(const float* __restrict__ vin, float* __restrict__ vout,
                           const int* __restrict__ row_ptr, const int* __restrict__ csr_src,
                           const float* __restrict__ dinv, int N) {
    int t = blockIdx.x * blockDim.x + threadIdx.x;
    int node = t >> 6;
    int lane = t & 63;
    if (node >= N) return;
    int beg = row_ptr[node];
    int end = row_ptr[node + 1];
    int deg = end - beg;

    float acc = 0.0f;
    if (lane < NC) acc = vin[(long long)node * NC + lane];

    int idx = 0;
    if (beg + lane < end) idx = csr_src[beg + lane];

    int m = (deg < 64) ? deg : 64;
#pragma unroll 4
    for (int k = 0; k < m; ++k) {
        int s = __shfl(idx, k);
        float v = 0.0f;
        if (lane < NC) v = vin[(long long)s * NC + lane];
        acc += v;
    }
    for (int k = 64; k < deg; ++k) {  // ~never taken (Poisson lambda=12.5)
        int s = csr_src[beg + k];
        float v = 0.0f;
        if (lane < NC) v = vin[(long long)s * NC + lane];
        acc += v;
    }

    float di = dinv[node];
    if (lane < NC) vout[(long long)node * NC + lane] = di * di * acc;
}

// Final hop fused with bias + relu + log_softmax, writes straight to out.
// logits[i] = dinv[i] * (vin[i] + sum vin[s]) + b
__global__ void hop_final_kernel(const float* __restrict__ vin, const float* __restrict__ b,
                                 float* __restrict__ out, const int* __restrict__ row_ptr,
                                 const int* __restrict__ csr_src, const float* __restrict__ dinv,
                                 int N) {
    int t = blockIdx.x * blockDim.x + threadIdx.x;
    int node = t >> 6;
    int lane = t & 63;
    if (node >= N) return;
    int beg = row_ptr[node];
    int end = row_ptr[node + 1];
    int deg = end - beg;

    float acc = 0.0f;
    if (lane < NC) acc = vin[(long long)node * NC + lane];

    int idx = 0;
    if (beg + lane < end) idx = csr_src[beg + lane];

    int m = (deg < 64) ? deg : 64;
#pragma unroll 4
    for (int k = 0; k < m; ++k) {
        int s = __shfl(idx, k);
        float v = 0.0f;
        if (lane < NC) v = vin[(long long)s * NC + lane];
        acc += v;
    }
    for (int k = 64; k < deg; ++k) {
        int s = csr_src[beg + k];
        float v = 0.0f;
        if (lane < NC) v = vin[(long long)s * NC + lane];
        acc += v;
    }

    float di = dinv[node];
    float bv = (lane < NC) ? b[lane] : 0.0f;
    float l = di * acc + bv;
    l = fmaxf(l, 0.0f);

    // max over lanes 0..39 (values >= 0, idle lanes contribute 0 -> harmless)
    float lm = (lane < NC) ? l : 0.0f;
#pragma unroll
    for (int off = 32; off > 0; off >>= 1) lm = fmaxf(lm, __shfl_xor(lm, off));
    float e = (lane < NC) ? __expf(l - lm) : 0.0f;
#pragma unroll
    for (int off = 32; off > 0; off >>= 1) e += __shfl_xor(e, off);
    float lse = lm + __logf(e);

    if (lane < NC) out[(long long)node * NC + lane] = l - lse;
}

extern "C" void kernel_launch(void* const* d_in, const int* in_sizes, int n_in,
                              void* d_out, int out_size, void* d_ws, size_t ws_size,
                              hipStream_t stream) {
    const float* x = (const float*)d_in[0];
    const void* ei = d_in[1];
    const float* W = (const float*)d_in[2];
    const float* b = (const float*)d_in[3];
    float* out = (float*)d_out;

    const int N = in_sizes[0] / NF;          // 100000
    const long long E = in_sizes[1] / 2;     // 1250000

    // workspace layout (256B aligned chunks)
    size_t off = 0;
    int* flag = (int*)((char*)d_ws + off);
    off += 256;
    int* cnt = (int*)((char*)d_ws + off);           // later reused as fill counters
    off += ((size_t)N * 4 + 255) & ~(size_t)255;
    int* row_ptr = (int*)((char*)d_ws + off);
    off += ((size_t)(N + 1) * 4 + 255) & ~(size_t)255;
    int* aux = (int*)((char*)d_ws + off);
    off += 1024;
    float* dinv = (float*)((char*)d_ws + off);
    off += ((size_t)N * 4 + 255) & ~(size_t)255;
    int* csr_src = (int*)((char*)d_ws + off);
    off += ((size_t)E * 4 + 255) & ~(size_t)255;
    float* z1 = (float*)((char*)d_ws + off);
    off += (((size_t)N * NC + 64) * 4 + 255) & ~(size_t)255;  // +slack, rows are 40 floats
    float* z2 = (float*)((char*)d_ws + off);
    off += (((size_t)N * NC + 64) * 4 + 255) & ~(size_t)255;
    if (off > ws_size) return;  // insufficient workspace

    const int B = 256;
    int gridN = (N + B - 1) / B;
    int gridE = (int)((E + B - 1) / B);
    int nScanBlocks = (N + SCAN_BLK - 1) / SCAN_BLK;  // 98
    int gridW = (int)(((long long)N * 64 + B - 1) / B);  // wave per node

    // 0. dtype detection
    int n_check = (int)((E < 65536) ? E : 65536);
    detect_dtype_kernel<<<1, 256, 0, stream>>>((const unsigned int*)ei, flag, n_check);

    // 1. CSR build: count -> scan -> fill ; dinv from degrees
    zero_cnt_kernel<<<gridN, B, 0, stream>>>(cnt, N);
    count_kernel<<<gridE, B, 0, stream>>>(ei, cnt, flag, E);
    scanA_kernel<<<nScanBlocks, 256, 0, stream>>>(cnt, row_ptr, aux, N);
    scanB_kernel<<<1, 128, 0, stream>>>(aux, nScanBlocks);
    scanC_kernel<<<gridN, B, 0, stream>>>(row_ptr, aux, cnt, dinv, N, (int)E);
    fill_kernel<<<gridE, B, 0, stream>>>(ei, row_ptr, cnt, csr_src, flag, E);

    // 2. v0 = D^{-1/2} (x W^T)   [N,40]
    zgemm_kernel<<<gridN, B, 0, stream>>>(x, W, dinv, z1, N);

    // 3. hops 1,2 in class space; hop 3 fused with bias+relu+log_softmax
    hop_kernel<<<gridW, B, 0, stream>>>(z1, z2, row_ptr, csr_src, dinv, N);
    hop_kernel<<<gridW, B, 0, stream>>>(z2, z1, row_ptr, csr_src, dinv, N);
    hop_final_kernel<<<gridW, B, 0, stream>>>(z1, b, out, row_ptr, csr_src, dinv, N);
}

// Round 4
// 558.504 us; speedup vs baseline: 1.1731x; 1.1731x over previous
//
#include <hip/hip_runtime.h>
#include <hip/hip_bf16.h>
#include <stdint.h>

#define NF 64
#define NC 40
#define SCAN_BLK 1024  // elements scanned per block (256 threads x 4)

// ---------------------------------------------------------------------------
// Detect whether edge_index was uploaded as int32 or int64.
// For int64 (values < 2^31), every odd 32-bit word is 0.
// flag = 1 -> int32, flag = 0 -> int64.
// ---------------------------------------------------------------------------
__global__ void detect_dtype_kernel(const unsigned int* __restrict__ p, int* __restrict__ flag,
                                    int n_check) {
    __shared__ int s_any;
    if (threadIdx.x == 0) s_any = 0;
    __syncthreads();
    int any = 0;
    for (int i = threadIdx.x; i < n_check; i += blockDim.x) {
        if (p[2 * i + 1] != 0u) any = 1;
    }
    if (any) atomicOr(&s_any, 1);
    __syncthreads();
    if (threadIdx.x == 0) *flag = s_any;
}

__device__ __forceinline__ long long load_idx(const void* p, long long i, int is32) {
    if (is32) return (long long)((const int*)p)[i];
    return ((const long long*)p)[i];
}

__global__ void zero_cnt_kernel(int* __restrict__ cnt, int N) {
    int i = blockIdx.x * blockDim.x + threadIdx.x;
    if (i < N) cnt[i] = 0;
}

// cnt[col[e]] += 1  (in-degree, without self loop)
__global__ void count_kernel(const void* __restrict__ ei, int* __restrict__ cnt,
                             const int* __restrict__ flag, long long E) {
    long long e = (long long)blockIdx.x * blockDim.x + threadIdx.x;
    if (e >= E) return;
    int is32 = *flag;
    int c = (int)load_idx(ei, E + e, is32);
    atomicAdd(&cnt[c], 1);
}

// Per-block exclusive scan of cnt into row_ptr (block-local), block totals -> aux
__global__ void scanA_kernel(const int* __restrict__ cnt, int* __restrict__ row_ptr,
                             int* __restrict__ aux, int N) {
    __shared__ int sd[256];
    int t = threadIdx.x;
    int base = blockIdx.x * SCAN_BLK + t * 4;
    int v[4];
    int s = 0;
#pragma unroll
    for (int j = 0; j < 4; ++j) {
        v[j] = (base + j < N) ? cnt[base + j] : 0;
        s += v[j];
    }
    sd[t] = s;
    __syncthreads();
#pragma unroll
    for (int off = 1; off < 256; off <<= 1) {
        int a = (t >= off) ? sd[t - off] : 0;
        __syncthreads();
        sd[t] += a;
        __syncthreads();
    }
    int run = sd[t] - s;  // exclusive offset of this thread within block
#pragma unroll
    for (int j = 0; j < 4; ++j) {
        if (base + j < N) row_ptr[base + j] = run;
        run += v[j];
    }
    if (t == 255) aux[blockIdx.x] = sd[255];
}

// Exclusive scan of block totals (nb <= 128), single block of 128 threads
__global__ void scanB_kernel(int* __restrict__ aux, int nb) {
    __shared__ int sd[128];
    int t = threadIdx.x;
    int v = (t < nb) ? aux[t] : 0;
    sd[t] = v;
    __syncthreads();
#pragma unroll
    for (int off = 1; off < 128; off <<= 1) {
        int a = (t >= off) ? sd[t - off] : 0;
        __syncthreads();
        sd[t] += a;
        __syncthreads();
    }
    if (t < nb) aux[t] = sd[t] - v;
}

// row_ptr[i] += aux[block(i)]; dinv[i] = rsqrt(1+cnt[i]); cnt[i] = 0 (reused as fill ctr)
__global__ void scanC_kernel(int* __restrict__ row_ptr, const int* __restrict__ aux,
                             int* __restrict__ cnt, float* __restrict__ dinv, int N, int E) {
    int i = blockIdx.x * blockDim.x + threadIdx.x;
    if (i < N) {
        row_ptr[i] += aux[i >> 10];
        int c = cnt[i];
        dinv[i] = rsqrtf(1.0f + (float)c);
        cnt[i] = 0;  // becomes the fill counter
    }
    if (i == 0) row_ptr[N] = E;
}

// csr_src[row_ptr[col]++] = row
__global__ void fill_kernel(const void* __restrict__ ei, const int* __restrict__ row_ptr,
                            int* __restrict__ fill, int* __restrict__ csr_src,
                            const int* __restrict__ flag, long long E) {
    long long e = (long long)blockIdx.x * blockDim.x + threadIdx.x;
    if (e >= E) return;
    int is32 = *flag;
    int r = (int)load_idx(ei, e, is32);
    int c = (int)load_idx(ei, E + e, is32);
    int pos = row_ptr[c] + atomicAdd(&fill[c], 1);
    csr_src[pos] = r;
}

// z[i][c] = dinv[i] * sum_f x[i][f] * W[c][f]    (v0 = D^{-1/2} x W^T)
// Streaming: thread = node, acc[40] in VGPRs, x float4s straight from global
// (independent loads pipelined under FMAs), W broadcast from 10KB LDS.
__global__ void zgemm_kernel(const float* __restrict__ x, const float* __restrict__ W,
                             const float* __restrict__ dinv, float* __restrict__ z, int N) {
    __shared__ float4 sW[NC * (NF / 4)];  // 10240 B
    for (int i = threadIdx.x; i < NC * (NF / 4); i += blockDim.x)
        sW[i] = ((const float4*)W)[i];
    __syncthreads();

    int node = blockIdx.x * blockDim.x + threadIdx.x;
    if (node >= N) return;

    const float4* xp = (const float4*)(x + (size_t)node * NF);
    float acc[NC];
#pragma unroll
    for (int c = 0; c < NC; ++c) acc[c] = 0.0f;

#pragma unroll
    for (int i = 0; i < NF / 4; ++i) {
        float4 xv = xp[i];
#pragma unroll
        for (int c = 0; c < NC; ++c) {
            float4 w = sW[c * (NF / 4) + i];  // wave-uniform -> LDS broadcast
            acc[c] += w.x * xv.x + w.y * xv.y + w.z * xv.z + w.w * xv.w;
        }
    }

    float di = dinv[node];
    float4* zp = (float4*)(z + (size_t)node * NC);
#pragma unroll
    for (int c4 = 0; c4 < NC / 4; ++c4) {
        float4 o;
        o.x = di * acc[4 * c4 + 0];
        o.y = di * acc[4 * c4 + 1];
        o.z = di * acc[4 * c4 + 2];
        o.w = di * acc[4 * c4 + 3];
        zp[c4] = o;
    }
}

// One wave per node, lanes 0..39 = class dims.
// vout[i] = dinv[i]^2 * (vin[i] + sum_{s in in(i)} vin[s])
// Neighbor indices prefetched lane-parallel (1 coalesced load), broadcast via shfl.
__global__ void hop_kernel(const float* __restrict__ vin, float* __restrict__ vout,
                           const int* __restrict__ row_ptr, const int* __restrict__ csr_src,
                           const float* __restrict__ dinv, int N) {
    int t = blockIdx.x * blockDim.x + threadIdx.x;
    int node = t >> 6;
    int lane = t & 63;
    if (node >= N) return;
    int beg = row_ptr[node];
    int end = row_ptr[node + 1];
    int deg = end - beg;

    float acc = 0.0f;
    if (lane < NC) acc = vin[(long long)node * NC + lane];

    int idx = 0;
    if (beg + lane < end) idx = csr_src[beg + lane];

    int m = (deg < 64) ? deg : 64;
#pragma unroll 4
    for (int k = 0; k < m; ++k) {
        int s = __shfl(idx, k);
        float v = 0.0f;
        if (lane < NC) v = vin[(long long)s * NC + lane];
        acc += v;
    }
    for (int k = 64; k < deg; ++k) {  // ~never taken (Poisson lambda=12.5)
        int s = csr_src[beg + k];
        float v = 0.0f;
        if (lane < NC) v = vin[(long long)s * NC + lane];
        acc += v;
    }

    float di = dinv[node];
    if (lane < NC) vout[(long long)node * NC + lane] = di * di * acc;
}

// Final hop fused with bias + relu + log_softmax, writes straight to out.
// logits[i] = dinv[i] * (vin[i] + sum vin[s]) + b
__global__ void hop_final_kernel(const float* __restrict__ vin, const float* __restrict__ b,
                                 float* __restrict__ out, const int* __restrict__ row_ptr,
                                 const int* __restrict__ csr_src, const float* __restrict__ dinv,
                                 int N) {
    int t = blockIdx.x * blockDim.x + threadIdx.x;
    int node = t >> 6;
    int lane = t & 63;
    if (node >= N) return;
    int beg = row_ptr[node];
    int end = row_ptr[node + 1];
    int deg = end - beg;

    float acc = 0.0f;
    if (lane < NC) acc = vin[(long long)node * NC + lane];

    int idx = 0;
    if (beg + lane < end) idx = csr_src[beg + lane];

    int m = (deg < 64) ? deg : 64;
#pragma unroll 4
    for (int k = 0; k < m; ++k) {
        int s = __shfl(idx, k);
        float v = 0.0f;
        if (lane < NC) v = vin[(long long)s * NC + lane];
        acc += v;
    }
    for (int k = 64; k < deg; ++k) {
        int s = csr_src[beg + k];
        float v = 0.0f;
        if (lane < NC) v = vin[(long long)s * NC + lane];
        acc += v;
    }

    float di = dinv[node];
    float bv = (lane < NC) ? b[lane] : 0.0f;
    float l = di * acc + bv;
    l = fmaxf(l, 0.0f);

    // max over lanes 0..39 (values >= 0, idle lanes contribute 0 -> harmless)
    float lm = (lane < NC) ? l : 0.0f;
#pragma unroll
    for (int off = 32; off > 0; off >>= 1) lm = fmaxf(lm, __shfl_xor(lm, off));
    float e = (lane < NC) ? __expf(l - lm) : 0.0f;
#pragma unroll
    for (int off = 32; off > 0; off >>= 1) e += __shfl_xor(e, off);
    float lse = lm + __logf(e);

    if (lane < NC) out[(long long)node * NC + lane] = l - lse;
}

extern "C" void kernel_launch(void* const* d_in, const int* in_sizes, int n_in,
                              void* d_out, int out_size, void* d_ws, size_t ws_size,
                              hipStream_t stream) {
    const float* x = (const float*)d_in[0];
    const void* ei = d_in[1];
    const float* W = (const float*)d_in[2];
    const float* b = (const float*)d_in[3];
    float* out = (float*)d_out;

    const int N = in_sizes[0] / NF;          // 100000
    const long long E = in_sizes[1] / 2;     // 1250000

    // workspace layout (256B aligned chunks)
    size_t off = 0;
    int* flag = (int*)((char*)d_ws + off);
    off += 256;
    int* cnt = (int*)((char*)d_ws + off);           // later reused as fill counters
    off += ((size_t)N * 4 + 255) & ~(size_t)255;
    int* row_ptr = (int*)((char*)d_ws + off);
    off += ((size_t)(N + 1) * 4 + 255) & ~(size_t)255;
    int* aux = (int*)((char*)d_ws + off);
    off += 1024;
    float* dinv = (float*)((char*)d_ws + off);
    off += ((size_t)N * 4 + 255) & ~(size_t)255;
    int* csr_src = (int*)((char*)d_ws + off);
    off += ((size_t)E * 4 + 255) & ~(size_t)255;
    float* z1 = (float*)((char*)d_ws + off);
    off += (((size_t)N * NC + 64) * 4 + 255) & ~(size_t)255;  // rows are 40 floats
    float* z2 = (float*)((char*)d_ws + off);
    off += (((size_t)N * NC + 64) * 4 + 255) & ~(size_t)255;
    if (off > ws_size) return;  // insufficient workspace

    const int B = 256;
    int gridN = (N + B - 1) / B;
    int gridE = (int)((E + B - 1) / B);
    int nScanBlocks = (N + SCAN_BLK - 1) / SCAN_BLK;  // 98
    int gridW = (int)(((long long)N * 64 + B - 1) / B);  // wave per node

    // 0. dtype detection (4K samples is plenty: P[int32 random has 4096 zero odd-words] ~ 0)
    int n_check = (int)((E < 4096) ? E : 4096);
    detect_dtype_kernel<<<1, 256, 0, stream>>>((const unsigned int*)ei, flag, n_check);

    // 1. CSR build: count -> scan -> fill ; dinv from degrees
    zero_cnt_kernel<<<gridN, B, 0, stream>>>(cnt, N);
    count_kernel<<<gridE, B, 0, stream>>>(ei, cnt, flag, E);
    scanA_kernel<<<nScanBlocks, 256, 0, stream>>>(cnt, row_ptr, aux, N);
    scanB_kernel<<<1, 128, 0, stream>>>(aux, nScanBlocks);
    scanC_kernel<<<gridN, B, 0, stream>>>(row_ptr, aux, cnt, dinv, N, (int)E);
    fill_kernel<<<gridE, B, 0, stream>>>(ei, row_ptr, cnt, csr_src, flag, E);

    // 2. v0 = D^{-1/2} (x W^T)   [N,40]  (streaming, 128-thread blocks)
    zgemm_kernel<<<(N + 127) / 128, 128, 0, stream>>>(x, W, dinv, z1, N);

    // 3. hops 1,2 in class space; hop 3 fused with bias+relu+log_softmax
    hop_kernel<<<gridW, B, 0, stream>>>(z1, z2, row_ptr, csr_src, dinv, N);
    hop_kernel<<<gridW, B, 0, stream>>>(z2, z1, row_ptr, csr_src, dinv, N);
    hop_final_kernel<<<gridW, B, 0, stream>>>(z1, b, out, row_ptr, csr_src, dinv, N);
}

// Round 5
// 506.982 us; speedup vs baseline: 1.2923x; 1.1016x over previous
//
#include <hip/hip_runtime.h>
#include <hip/hip_bf16.h>
#include <hip/hip_fp16.h>
#include <stdint.h>

#define NF 64
#define NC 40
#define SCAN_BLK 1024  // elements scanned per block (256 threads x 4)
#define ZB 128         // zgemm: threads (= nodes) per block
#define XPAD 68        // zgemm: padded LDS row stride in floats (16B-aligned b128 reads)

// ---------------------------------------------------------------------------
// Detect whether edge_index was uploaded as int32 or int64.
// For int64 (values < 2^31), every odd 32-bit word is 0.
// flag = 1 -> int32, flag = 0 -> int64.
// ---------------------------------------------------------------------------
__global__ void detect_dtype_kernel(const unsigned int* __restrict__ p, int* __restrict__ flag,
                                    int n_check) {
    __shared__ int s_any;
    if (threadIdx.x == 0) s_any = 0;
    __syncthreads();
    int any = 0;
    for (int i = threadIdx.x; i < n_check; i += blockDim.x) {
        if (p[2 * i + 1] != 0u) any = 1;
    }
    if (any) atomicOr(&s_any, 1);
    __syncthreads();
    if (threadIdx.x == 0) *flag = s_any;
}

__device__ __forceinline__ long long load_idx(const void* p, long long i, int is32) {
    if (is32) return (long long)((const int*)p)[i];
    return ((const long long*)p)[i];
}

__global__ void zero_cnt_kernel(int* __restrict__ cnt, int N) {
    int i = blockIdx.x * blockDim.x + threadIdx.x;
    if (i < N) cnt[i] = 0;
}

// cnt[col[e]] += 1  (in-degree, without self loop)
__global__ void count_kernel(const void* __restrict__ ei, int* __restrict__ cnt,
                             const int* __restrict__ flag, long long E) {
    long long e = (long long)blockIdx.x * blockDim.x + threadIdx.x;
    if (e >= E) return;
    int is32 = *flag;
    int c = (int)load_idx(ei, E + e, is32);
    atomicAdd(&cnt[c], 1);
}

// Per-block exclusive scan of cnt into row_ptr (block-local), block totals -> aux
__global__ void scanA_kernel(const int* __restrict__ cnt, int* __restrict__ row_ptr,
                             int* __restrict__ aux, int N) {
    __shared__ int sd[256];
    int t = threadIdx.x;
    int base = blockIdx.x * SCAN_BLK + t * 4;
    int v[4];
    int s = 0;
#pragma unroll
    for (int j = 0; j < 4; ++j) {
        v[j] = (base + j < N) ? cnt[base + j] : 0;
        s += v[j];
    }
    sd[t] = s;
    __syncthreads();
#pragma unroll
    for (int off = 1; off < 256; off <<= 1) {
        int a = (t >= off) ? sd[t - off] : 0;
        __syncthreads();
        sd[t] += a;
        __syncthreads();
    }
    int run = sd[t] - s;  // exclusive offset of this thread within block
#pragma unroll
    for (int j = 0; j < 4; ++j) {
        if (base + j < N) row_ptr[base + j] = run;
        run += v[j];
    }
    if (t == 255) aux[blockIdx.x] = sd[255];
}

// Exclusive scan of block totals (nb <= 128), single block of 128 threads
__global__ void scanB_kernel(int* __restrict__ aux, int nb) {
    __shared__ int sd[128];
    int t = threadIdx.x;
    int v = (t < nb) ? aux[t] : 0;
    sd[t] = v;
    __syncthreads();
#pragma unroll
    for (int off = 1; off < 128; off <<= 1) {
        int a = (t >= off) ? sd[t - off] : 0;
        __syncthreads();
        sd[t] += a;
        __syncthreads();
    }
    if (t < nb) aux[t] = sd[t] - v;
}

// row_ptr[i] += aux[block(i)]; dinv[i] = rsqrt(1+cnt[i]); cnt[i] = 0 (reused as fill ctr)
__global__ void scanC_kernel(int* __restrict__ row_ptr, const int* __restrict__ aux,
                             int* __restrict__ cnt, float* __restrict__ dinv, int N, int E) {
    int i = blockIdx.x * blockDim.x + threadIdx.x;
    if (i < N) {
        row_ptr[i] += aux[i >> 10];
        int c = cnt[i];
        dinv[i] = rsqrtf(1.0f + (float)c);
        cnt[i] = 0;  // becomes the fill counter
    }
    if (i == 0) row_ptr[N] = E;
}

// csr_src[row_ptr[col]++] = row
__global__ void fill_kernel(const void* __restrict__ ei, const int* __restrict__ row_ptr,
                            int* __restrict__ fill, int* __restrict__ csr_src,
                            const int* __restrict__ flag, long long E) {
    long long e = (long long)blockIdx.x * blockDim.x + threadIdx.x;
    if (e >= E) return;
    int is32 = *flag;
    int r = (int)load_idx(ei, e, is32);
    int c = (int)load_idx(ei, E + e, is32);
    int pos = row_ptr[c] + atomicAdd(&fill[c], 1);
    csr_src[pos] = r;
}

// z[i][c] = half( dinv[i] * sum_f x[i][f] * W[c][f] )    (v0 = D^{-1/2} x W^T)
// x staged into LDS with fully-coalesced float4 loads; thread = node reads its
// own padded row from LDS; W broadcast from 10KB LDS (wave-uniform addresses).
__global__ void zgemm_kernel(const float* __restrict__ x, const float* __restrict__ W,
                             const float* __restrict__ dinv, __half* __restrict__ z, int N) {
    __shared__ float4 sW[NC * (NF / 4)];   // 10240 B
    __shared__ float sX[ZB * XPAD];        // 34816 B
    for (int i = threadIdx.x; i < NC * (NF / 4); i += ZB)
        sW[i] = ((const float4*)W)[i];

    int base = blockIdx.x * ZB;
    int nrows = N - base;
    if (nrows > ZB) nrows = ZB;
    // coalesced stage: g4-th float4 of this block's x slab -> padded LDS row
    const float4* xg = (const float4*)(x + (size_t)base * NF);
    for (int g4 = threadIdx.x; g4 < nrows * (NF / 4); g4 += ZB) {
        int n = g4 >> 4;
        int i = g4 & 15;
        *((float4*)&sX[n * XPAD + i * 4]) = xg[g4];
    }
    __syncthreads();

    int node = base + threadIdx.x;
    if (node >= N) return;

    float acc[NC];
#pragma unroll
    for (int c = 0; c < NC; ++c) acc[c] = 0.0f;

#pragma unroll
    for (int i = 0; i < NF / 4; ++i) {
        float4 xv = *((const float4*)&sX[threadIdx.x * XPAD + i * 4]);
#pragma unroll
        for (int c = 0; c < NC; ++c) {
            float4 w = sW[c * (NF / 4) + i];  // wave-uniform -> broadcast
            acc[c] += w.x * xv.x + w.y * xv.y + w.z * xv.z + w.w * xv.w;
        }
    }

    float di = dinv[node];
    __half2* zp = (__half2*)(z + (size_t)node * NC);  // 80B rows -> 4B aligned
#pragma unroll
    for (int p = 0; p < NC / 2; ++p)
        zp[p] = __floats2half2_rn(di * acc[2 * p], di * acc[2 * p + 1]);
}

// One wave per node, lanes 0..39 = class dims. fp16 rows = 80B (2 cache lines/gather).
// vout[i] = half( dinv[i]^2 * (vin[i] + sum_{s in in(i)} vin[s]) )
__global__ void hop_kernel(const __half* __restrict__ vin, __half* __restrict__ vout,
                           const int* __restrict__ row_ptr, const int* __restrict__ csr_src,
                           const float* __restrict__ dinv, int N) {
    int t = blockIdx.x * blockDim.x + threadIdx.x;
    int node = t >> 6;
    int lane = t & 63;
    if (node >= N) return;
    int beg = row_ptr[node];
    int end = row_ptr[node + 1];
    int deg = end - beg;

    float acc = 0.0f;
    if (lane < NC) acc = __half2float(vin[(size_t)node * NC + lane]);

    int idx = 0;
    if (beg + lane < end) idx = csr_src[beg + lane];

    int m = (deg < 64) ? deg : 64;
#pragma unroll 4
    for (int k = 0; k < m; ++k) {
        int s = __shfl(idx, k);
        float v = 0.0f;
        if (lane < NC) v = __half2float(vin[(size_t)s * NC + lane]);
        acc += v;
    }
    for (int k = 64; k < deg; ++k) {  // ~never taken (Poisson lambda=12.5)
        int s = csr_src[beg + k];
        float v = 0.0f;
        if (lane < NC) v = __half2float(vin[(size_t)s * NC + lane]);
        acc += v;
    }

    float di = dinv[node];
    if (lane < NC) vout[(size_t)node * NC + lane] = __float2half(di * di * acc);
}

// Final hop fused with bias + relu + log_softmax, writes fp32 straight to out.
// logits[i] = dinv[i] * (vin[i] + sum vin[s]) + b
__global__ void hop_final_kernel(const __half* __restrict__ vin, const float* __restrict__ b,
                                 float* __restrict__ out, const int* __restrict__ row_ptr,
                                 const int* __restrict__ csr_src, const float* __restrict__ dinv,
                                 int N) {
    int t = blockIdx.x * blockDim.x + threadIdx.x;
    int node = t >> 6;
    int lane = t & 63;
    if (node >= N) return;
    int beg = row_ptr[node];
    int end = row_ptr[node + 1];
    int deg = end - beg;

    float acc = 0.0f;
    if (lane < NC) acc = __half2float(vin[(size_t)node * NC + lane]);

    int idx = 0;
    if (beg + lane < end) idx = csr_src[beg + lane];

    int m = (deg < 64) ? deg : 64;
#pragma unroll 4
    for (int k = 0; k < m; ++k) {
        int s = __shfl(idx, k);
        float v = 0.0f;
        if (lane < NC) v = __half2float(vin[(size_t)s * NC + lane]);
        acc += v;
    }
    for (int k = 64; k < deg; ++k) {
        int s = csr_src[beg + k];
        float v = 0.0f;
        if (lane < NC) v = __half2float(vin[(size_t)s * NC + lane]);
        acc += v;
    }

    float di = dinv[node];
    float bv = (lane < NC) ? b[lane] : 0.0f;
    float l = di * acc + bv;
    l = fmaxf(l, 0.0f);

    // max over lanes 0..39 (values >= 0, idle lanes contribute 0 -> harmless)
    float lm = (lane < NC) ? l : 0.0f;
#pragma unroll
    for (int off = 32; off > 0; off >>= 1) lm = fmaxf(lm, __shfl_xor(lm, off));
    float e = (lane < NC) ? __expf(l - lm) : 0.0f;
#pragma unroll
    for (int off = 32; off > 0; off >>= 1) e += __shfl_xor(e, off);
    float lse = lm + __logf(e);

    if (lane < NC) out[(size_t)node * NC + lane] = l - lse;
}

extern "C" void kernel_launch(void* const* d_in, const int* in_sizes, int n_in,
                              void* d_out, int out_size, void* d_ws, size_t ws_size,
                              hipStream_t stream) {
    const float* x = (const float*)d_in[0];
    const void* ei = d_in[1];
    const float* W = (const float*)d_in[2];
    const float* b = (const float*)d_in[3];
    float* out = (float*)d_out;

    const int N = in_sizes[0] / NF;          // 100000
    const long long E = in_sizes[1] / 2;     // 1250000

    // workspace layout (256B aligned chunks)
    size_t off = 0;
    int* flag = (int*)((char*)d_ws + off);
    off += 256;
    int* cnt = (int*)((char*)d_ws + off);           // later reused as fill counters
    off += ((size_t)N * 4 + 255) & ~(size_t)255;
    int* row_ptr = (int*)((char*)d_ws + off);
    off += ((size_t)(N + 1) * 4 + 255) & ~(size_t)255;
    int* aux = (int*)((char*)d_ws + off);
    off += 1024;
    float* dinv = (float*)((char*)d_ws + off);
    off += ((size_t)N * 4 + 255) & ~(size_t)255;
    int* csr_src = (int*)((char*)d_ws + off);
    off += ((size_t)E * 4 + 255) & ~(size_t)255;
    __half* z1 = (__half*)((char*)d_ws + off);
    off += (((size_t)N * NC + 64) * 2 + 255) & ~(size_t)255;  // rows are 40 halfs (80B)
    __half* z2 = (__half*)((char*)d_ws + off);
    off += (((size_t)N * NC + 64) * 2 + 255) & ~(size_t)255;
    if (off > ws_size) return;  // insufficient workspace

    const int B = 256;
    int gridN = (N + B - 1) / B;
    int gridE = (int)((E + B - 1) / B);
    int nScanBlocks = (N + SCAN_BLK - 1) / SCAN_BLK;  // 98
    int gridW = (int)(((long long)N * 64 + B - 1) / B);  // wave per node

    // 0. dtype detection
    int n_check = (int)((E < 4096) ? E : 4096);
    detect_dtype_kernel<<<1, 256, 0, stream>>>((const unsigned int*)ei, flag, n_check);

    // 1. CSR build: count -> scan -> fill ; dinv from degrees
    zero_cnt_kernel<<<gridN, B, 0, stream>>>(cnt, N);
    count_kernel<<<gridE, B, 0, stream>>>(ei, cnt, flag, E);
    scanA_kernel<<<nScanBlocks, 256, 0, stream>>>(cnt, row_ptr, aux, N);
    scanB_kernel<<<1, 128, 0, stream>>>(aux, nScanBlocks);
    scanC_kernel<<<gridN, B, 0, stream>>>(row_ptr, aux, cnt, dinv, N, (int)E);
    fill_kernel<<<gridE, B, 0, stream>>>(ei, row_ptr, cnt, csr_src, flag, E);

    // 2. v0 = D^{-1/2} (x W^T)   [N,40] in fp16  (LDS-staged coalesced x)
    zgemm_kernel<<<(N + ZB - 1) / ZB, ZB, 0, stream>>>(x, W, dinv, z1, N);

    // 3. hops 1,2 in class space (fp16); hop 3 fused with bias+relu+log_softmax
    hop_kernel<<<gridW, B, 0, stream>>>(z1, z2, row_ptr, csr_src, dinv, N);
    hop_kernel<<<gridW, B, 0, stream>>>(z2, z1, row_ptr, csr_src, dinv, N);
    hop_final_kernel<<<gridW, B, 0, stream>>>(z1, b, out, row_ptr, csr_src, dinv, N);
}